// Round 26
// baseline (296.307 us; speedup 1.0000x reference)
//
#include <hip/hip_runtime.h>
#include <math.h>

#define NPTS 4096
#define KNN 16
#define TBINS 352
#define PPB 8                  // points per block (kernel A; 128-thread blocks)
#define TPB 128                // threads per block (kernel A)
#define CITER (NPTS / 16)      // 256 candidates per lane (16 lanes/point)
#define CAP 96                 // survivor capacity per point
#define BINOFF 210             // (bits>>22) offset: bins cover d2 in [2^-22, ~2^9.5]
#define HROW 68                // hist row stride in bytes (17 dwords, coprime 32)

// ---------------------------------------------------------------------------
// sorted ascending insert into u64 K[16] (lex key = (d2bits<<32)|idx)
// ---------------------------------------------------------------------------
__device__ __forceinline__ void ins16(unsigned long long* K, unsigned long long key) {
  if (key < K[15]) {
#pragma unroll
    for (int q = 15; q >= 1; --q) {
      bool ltm = key < K[q - 1];
      bool ltk = key < K[q];
      K[q] = ltm ? K[q - 1] : (ltk ? key : K[q]);
    }
    if (key < K[0]) K[0] = key;
  }
}

#define JROT(App, Aqq, Apq, Arp, Arq, V0p, V0q, V1p, V1q, V2p, V2q)            \
  do {                                                                         \
    double apq_ = Apq;                                                         \
    if (fabs(apq_) > 1e-300) {                                                 \
      double tau_ = (Aqq - App) / (2.0 * apq_);                                \
      double t_ = (tau_ >= 0.0) ? 1.0 / (tau_ + sqrt(1.0 + tau_ * tau_))       \
                                : 1.0 / (tau_ - sqrt(1.0 + tau_ * tau_));      \
      double c_ = 1.0 / sqrt(1.0 + t_ * t_);                                   \
      double s_ = t_ * c_;                                                     \
      App = App - t_ * apq_;                                                   \
      Aqq = Aqq + t_ * apq_;                                                   \
      Apq = 0.0;                                                               \
      double u_, w_;                                                           \
      u_ = Arp; w_ = Arq; Arp = c_ * u_ - s_ * w_; Arq = s_ * u_ + c_ * w_;    \
      u_ = V0p; w_ = V0q; V0p = c_ * u_ - s_ * w_; V0q = s_ * u_ + c_ * w_;    \
      u_ = V1p; w_ = V1q; V1p = c_ * u_ - s_ * w_; V1q = s_ * u_ + c_ * w_;    \
      u_ = V2p; w_ = V2q; V2p = c_ * u_ - s_ * w_; V2q = s_ * u_ + c_ * w_;    \
    }                                                                          \
  } while (0)

// ---------------------------------------------------------------------------
// Kernel T: AoS -> SoA transpose (xs, ys, zs). One-shot, ~3 µs.
// ---------------------------------------------------------------------------
__global__ __launch_bounds__(256) void soa_kernel(
    const float* __restrict__ verts,
    float* __restrict__ xs, float* __restrict__ ys, float* __restrict__ zs)
{
  const int g = blockIdx.x * 256 + (int)threadIdx.x; // 0..32767
  xs[g] = verts[3 * g + 0];
  ys[g] = verts[3 * g + 1];
  zs[g] = verts[3 * g + 2];
}

// ---------------------------------------------------------------------------
// Kernel A: 16-NN selection -> nbr_idx, + per-block radius^2 reduction.
// Round-25 experiment (single variable vs the 3x-measured 222 µs config):
// 128-thread blocks (PPB=8). Selection logic byte-identical (16 lanes/point,
// same CITER/bins/CAP); only block geometry changes. LDS 32.3 -> 16.3 KB
// per block -> 9-10 blocks/CU x 2 waves = 18-20 waves/CU (was 16 cap /
// 40% measured) -> +25% TLP to hide L2-load + LDS-RMW latency.
// ---------------------------------------------------------------------------
__global__ __launch_bounds__(TPB, 2) void knn_select_kernel(
    const float* __restrict__ xs,           // (8*4096) SoA
    const float* __restrict__ ys,
    const float* __restrict__ zs,
    int* __restrict__ nbr_idx,              // (8*4096,16)
    unsigned int* __restrict__ rad2_bits)   // (8), f32 d2 bits, init 0
{
  __shared__ unsigned char hist[TPB * HROW];      //  8704 B, lane-private rows
  __shared__ unsigned short ptot[PPB][64];        //  1024 B
  __shared__ unsigned long long surv[PPB][CAP];   //  6144 B
  __shared__ unsigned int scnt[PPB];
  __shared__ unsigned int tbl[PPB];
  __shared__ unsigned int radsh[PPB];

  const int blk = blockIdx.x;       // 4096 blocks = 8 clouds * 512
  const int cloud = blk >> 9;
  const int pbase = (blk & 511) * PPB;
  const int cb = cloud << 12;       // cloud base into SoA arrays
  const float* __restrict__ xb = xs + cb;
  const float* __restrict__ yb = ys + cb;
  const float* __restrict__ zb = zs + cb;
  const int tid = (int)threadIdx.x;

  {
    unsigned int* h32 = (unsigned int*)hist;
#pragma unroll
    for (int k = 0; k < 17; ++k) h32[tid * 17 + k] = 0u;  // own padded row
  }
  if (tid < PPB) scnt[tid] = 0u;
  __syncthreads();

  const int p = tid >> 4;           // point-in-block, 0..7
  const int c = tid & 15;           // lane-in-point
  const int i = pbase + p;
  const float xi = xb[i], yi = yb[i], zi = zb[i];

  // ---- pass 1: exact-bits histogram ----------------------------------------
#pragma unroll 4
  for (int s = 0; s < CITER; ++s) {
    const int j = (s << 4) | c;
    float dx = __fsub_rn(xb[j], xi);
    float dy = __fsub_rn(yb[j], yi);
    float dz = __fsub_rn(zb[j], zi);
    float d2 = __fadd_rn(__fadd_rn(__fmul_rn(dx, dx), __fmul_rn(dy, dy)),
                         __fmul_rn(dz, dz));
    int b = (int)(__float_as_uint(d2) >> 22) - BINOFF;
    b = min(max(b, 0), 63);
    hist[tid * HROW + b] += (unsigned char)1;
  }
  __syncthreads();

  // ---- reduce lane-private rows -> per-point totals ------------------------
#pragma unroll
  for (int bq = 0; bq < 4; ++bq) {
    int b = 4 * c + bq;
    unsigned int tot = 0;
    for (int r = 0; r < 16; ++r) tot += hist[(p * 16 + r) * HROW + b];
    ptot[p][b] = (unsigned short)tot;
  }
  __syncthreads();

  // ---- exact threshold: first bin where cumcount >= 16 ---------------------
  if (c == 0) {
    unsigned int cum = 0; int B = 63;
    for (int b = 0; b < 64; ++b) {
      cum += ptot[p][b];
      if (cum >= KNN) { B = b; break; }
    }
    // bin 63 is clamped: its edge doesn't bound contents -> accept all
    tbl[p] = (B >= 63) ? 0xFFFFFFFFu : ((unsigned int)(B + 1 + BINOFF) << 22);
  }
  __syncthreads();

  // ---- pass 2: collect survivors -------------------------------------------
  {
    const unsigned int T = tbl[p];
#pragma unroll 4
    for (int s = 0; s < CITER; ++s) {
      const int j = (s << 4) | c;
      float dx = __fsub_rn(xb[j], xi);
      float dy = __fsub_rn(yb[j], yi);
      float dz = __fsub_rn(zb[j], zi);
      float d2 = __fadd_rn(__fadd_rn(__fmul_rn(dx, dx), __fmul_rn(dy, dy)),
                           __fmul_rn(dz, dz));
      unsigned int bits = __float_as_uint(d2);
      if (bits < T) {
        unsigned int pos = atomicAdd(&scnt[p], 1u);
        if (pos < CAP) surv[p][pos] = ((unsigned long long)bits << 32) | (unsigned int)j;
      }
    }
  }
  __syncthreads();

  // ---- handler lane: exact top-16 among survivors (lex == top_k order) -----
  if (c == 0) {
    unsigned long long K[KNN];
#pragma unroll
    for (int k = 0; k < KNN; ++k) K[k] = 0xFFFFFFFFFFFFFFFFull;
    const int n = (int)scnt[p];
    if (n <= CAP) {
      for (int t = 0; t < n; ++t) ins16(K, surv[p][t]);
    } else {
      // exact fallback: serial full re-scan (never expected at 64 bins)
      for (int j = 0; j < NPTS; ++j) {
        float dx = __fsub_rn(xb[j], xi);
        float dy = __fsub_rn(yb[j], yi);
        float dz = __fsub_rn(zb[j], zi);
        float d2 = __fadd_rn(__fadd_rn(__fmul_rn(dx, dx), __fmul_rn(dy, dy)),
                             __fmul_rn(dz, dz));
        ins16(K, ((unsigned long long)__float_as_uint(d2) << 32) | (unsigned int)j);
      }
    }
    const int gp = cloud * NPTS + i;
#pragma unroll
    for (int k = 0; k < KNN; ++k) nbr_idx[gp * KNN + k] = (int)(K[k] & 0xFFFFFFFFull);
    radsh[p] = (unsigned int)(K[KNN - 1] >> 32);  // 16th-NN d2 bits
  }
  __syncthreads();

  // ---- ONE atomic per block: block max of 8 per-point d2 bits --------------
  if (tid == 0) {
    unsigned int m = radsh[0];
#pragma unroll
    for (int q = 1; q < PPB; ++q) m = max(m, radsh[q]);
    atomicMax(&rad2_bits[cloud], m);
  }
}

// ---------------------------------------------------------------------------
// Kernel B: normals, 16 LANES PER POINT (scalarized, no local arrays, no
// contended atomics). Unchanged from the measured-good config.
// ---------------------------------------------------------------------------
__global__ __launch_bounds__(256, 1) void normal_kernel(
    const float* __restrict__ verts,
    const int* __restrict__ nbr_idx,
    float* __restrict__ normals)            // (8*4096,3)
{
  const int t = blockIdx.x * 256 + (int)threadIdx.x; // 0 .. 524287
  const int gp = t >> 4;            // point, 0..32767
  const int c = t & 15;             // neighbor slot
  const int cloud = gp >> 12;
  const int i = gp & (NPTS - 1);
  const float* __restrict__ vb = verts + (size_t)cloud * NPTS * 3;
  const float xi = vb[3 * i + 0], yi = vb[3 * i + 1], zi = vb[3 * i + 2];

  const int id = nbr_idx[gp * KNN + c];  // coalesced: 16 consecutive per point
  const float* vp = vb + 3 * id;
  const float dx = __fsub_rn(vp[0], xi);
  const float dy = __fsub_rn(vp[1], yi);
  const float dz = __fsub_rn(vp[2], zi);
  const float d2 = __fadd_rn(__fadd_rn(__fmul_rn(dx, dx), __fmul_rn(dy, dy)),
                             __fmul_rn(dz, dz));
  const double dist = sqrt((double)d2);
  const double radius_i = __shfl(dist, 15, 16); // lane 15 of each 16-group

  double w = radius_i - dist;
  if (w < 0.0) w = 0.0;
  const double dxd = (double)dx, dyd = (double)dy, dzd = (double)dz;
  const double wx = w * dxd, wy = w * dyd;
  double c00 = wx * dxd, c01 = wx * dyd, c02 = wx * dzd;
  double c11 = wy * dyd, c12 = wy * dzd, c22 = (w * dzd) * dzd;
  double sw = w;

  // butterfly sum within the 16-lane group (xor masks < 16 stay in-group)
#pragma unroll
  for (int m = 8; m >= 1; m >>= 1) {
    c00 += __shfl_xor(c00, m);
    c01 += __shfl_xor(c01, m);
    c02 += __shfl_xor(c02, m);
    c11 += __shfl_xor(c11, m);
    c12 += __shfl_xor(c12, m);
    c22 += __shfl_xor(c22, m);
    sw  += __shfl_xor(sw,  m);
  }

  const double inv = 1.0 / (sw + 1e-8);
  c00 *= inv; c01 *= inv; c02 *= inv; c11 *= inv; c12 *= inv; c22 *= inv;

  // all 16 lanes run the identical scalar Jacobi (uniform, no divergence)
  double A00 = c00, A01 = c01, A02 = c02, A11 = c11, A12 = c12, A22 = c22;
  double v00 = 1, v01 = 0, v02 = 0,
         v10 = 0, v11 = 1, v12 = 0,
         v20 = 0, v21 = 0, v22 = 1;
  for (int sweep = 0; sweep < 8; ++sweep) {
    JROT(A00, A11, A01, A02, A12, v00, v01, v10, v11, v20, v21);
    JROT(A00, A22, A02, A01, A12, v00, v02, v10, v12, v20, v22);
    JROT(A11, A22, A12, A01, A02, v01, v02, v11, v12, v21, v22);
  }

  double nx, ny, nz;
  if (A00 <= A11 && A00 <= A22)      { nx = v00; ny = v10; nz = v20; }
  else if (A11 <= A22)               { nx = v01; ny = v11; nz = v21; }
  else                               { nx = v02; ny = v12; nz = v22; }
  const double rn = 1.0 / sqrt(nx * nx + ny * ny + nz * nz);
  nx *= rn; ny *= rn; nz *= rn;

  // sign vote: each lane contributes its own neighbor's projection sign
  const double pr = dxd * nx + dyd * ny + dzd * nz;
  int sv = (pr > 0.0) - (pr < 0.0);
#pragma unroll
  for (int m = 8; m >= 1; m >>= 1) sv += __shfl_xor(sv, m);
  if (sv < 0) { nx = -nx; ny = -ny; nz = -nz; }

  if (c == 0) {
    normals[3 * gp + 0] = (float)nx;
    normals[3 * gp + 1] = (float)ny;
    normals[3 * gp + 2] = (float)nz;
  }
}

// ---------------------------------------------------------------------------
// Kernel B1: per point, 16 flat bins + normalization denominator.
// radius = f32(sqrt_f64(max d2)) — bit-identical to old max-of-radii.
// ---------------------------------------------------------------------------
__global__ __launch_bounds__(256) void bins_kernel(
    const float* __restrict__ verts,
    const float* __restrict__ normals,
    const int* __restrict__ nbr_idx,
    const unsigned int* __restrict__ rad2_bits,
    unsigned short* __restrict__ bins,
    float* __restrict__ denoms)
{
  const int gp = blockIdx.x * 256 + threadIdx.x;
  const int cloud = gp >> 12;
  const int i = gp & (NPTS - 1);
  const float* __restrict__ vb = verts + (size_t)cloud * NPTS * 3;
  const float xi = vb[3 * i + 0], yi = vb[3 * i + 1], zi = vb[3 * i + 2];
  const float nxi = normals[3 * gp + 0];
  const float nyi = normals[3 * gp + 1];
  const float nzi = normals[3 * gp + 2];
  const float radius = (float)sqrt((double)__uint_as_float(rad2_bits[cloud]));
  const float rpe = __fadd_rn(radius, 1e-8f);
  const float PI_F = 3.14159274101257324f;
  const float TWOPI_F = 6.28318548202514648f;

  int bl[KNN];
#pragma unroll
  for (int k = 0; k < KNN; ++k) {
    int j = nbr_idx[gp * KNN + k];
    float dx = __fsub_rn(vb[3 * j + 0], xi);
    float dy = __fsub_rn(vb[3 * j + 1], yi);
    float dz = __fsub_rn(vb[3 * j + 2], zi);
    float d2f = __fadd_rn(__fadd_rn(__fmul_rn(dx, dx), __fmul_rn(dy, dy)),
                          __fmul_rn(dz, dz));
    float r = (float)sqrt((double)d2f);

    float az = (float)atan2((double)dy, (double)dx);
    int azb = (int)__fmul_rn(__fdiv_rn(__fadd_rn(az, PI_F), TWOPI_F), 8.0f);
    azb = min(max(azb, 0), 7);

    float el = __fmul_rn(__fadd_rn(__fdiv_rn(dz, __fadd_rn(r, 1e-8f)), 1.0f), 0.5f);
    int elb = (int)__fmul_rn(el, 2.0f);
    elb = min(max(elb, 0), 1);

    int rb = (int)__fmul_rn(__fdiv_rn(r, rpe), 2.0f);
    rb = min(max(rb, 0), 1);

    int gj = cloud * NPTS + j;
    double cd = (double)nxi * (double)normals[3 * gj + 0] +
                (double)nyi * (double)normals[3 * gj + 1] +
                (double)nzi * (double)normals[3 * gj + 2];
    cd = fmin(fmax(cd, -1.0), 1.0);
    float cf = (float)cd;
    int hb = (int)__fmul_rn(__fmul_rn(__fadd_rn(cf, 1.0f), 0.5f), 11.0f);
    hb = min(max(hb, 0), 10);

    bl[k] = ((azb * 2 + elb) * 2 + rb) * 11 + hb;
  }

  int pairs = 0;
#pragma unroll
  for (int a = 0; a < KNN; ++a)
#pragma unroll
    for (int b = 0; b < KNN; ++b) pairs += (bl[a] == bl[b]) ? 1 : 0;

  denoms[gp] = __fadd_rn(sqrtf((float)pairs), 1e-8f);
  unsigned short* bp = bins + (size_t)gp * KNN;
#pragma unroll
  for (int k = 0; k < KNN; ++k) bp[k] = (unsigned short)bl[k];
}

// ---------------------------------------------------------------------------
// Kernel B2: expand to dense (8,4096,352) output (unchanged).
// ---------------------------------------------------------------------------
__global__ __launch_bounds__(256) void out_kernel(
    const unsigned short* __restrict__ bins,
    const float* __restrict__ denoms,
    float* __restrict__ out)
{
  const int gid = blockIdx.x * 256 + threadIdx.x;
  const int p = gid / TBINS;
  const int b = gid - p * TBINS;
  const unsigned short* __restrict__ bp = bins + (size_t)p * KNN;
  int c = 0;
#pragma unroll
  for (int k = 0; k < KNN; ++k) c += (bp[k] == (unsigned short)b) ? 1 : 0;
  out[gid] = __fdiv_rn((float)c, denoms[p]);
}

// ---------------------------------------------------------------------------
extern "C" void kernel_launch(void* const* d_in, const int* in_sizes, int n_in,
                              void* d_out, int out_size, void* d_ws, size_t ws_size,
                              hipStream_t stream) {
  const float* verts = (const float*)d_in[0];
  float* out = (float*)d_out;

  char* ws = (char*)d_ws;
  float* normals = (float*)ws;                              // 384 KiB
  int* nidx = (int*)(ws + 393216);                          // 2 MiB
  unsigned short* bins = (unsigned short*)(ws + 2490368);   // 1 MiB
  float* denoms = (float*)(ws + 3538944);                   // 128 KiB
  unsigned int* radb = (unsigned int*)(ws + 3670016);       // 32 B
  float* xs = (float*)(ws + 3670048);                       // 128 KiB
  float* ys = (float*)(ws + 3801120);                       // 128 KiB
  float* zs = (float*)(ws + 3932192);                       // 128 KiB

  hipMemsetAsync(radb, 0, 8 * sizeof(unsigned int), stream);

  soa_kernel<<<128, 256, 0, stream>>>(verts, xs, ys, zs);
  knn_select_kernel<<<4096, TPB, 0, stream>>>(xs, ys, zs, nidx, radb);
  normal_kernel<<<2048, 256, 0, stream>>>(verts, nidx, normals);
  bins_kernel<<<128, 256, 0, stream>>>(verts, normals, nidx, radb, bins, denoms);
  const int total = 8 * NPTS * TBINS;
  out_kernel<<<total / 256, 256, 0, stream>>>(bins, denoms, out);
}

// Round 27
// 288.398 us; speedup vs baseline: 1.0274x; 1.0274x over previous
//
#include <hip/hip_runtime.h>
#include <math.h>

#define NPTS 4096
#define KNN 16
#define TBINS 352
#define PPB 16                 // points per block (kernel A)
#define CITER (NPTS / 16)      // 256 candidates per lane (16 lanes/point)
#define CAP 96                 // survivor capacity per point
#define BINOFF 210             // (bits>>22) offset: bins cover d2 in [2^-22, ~2^9.5]
#define HROW 68                // hist row stride in bytes (17 dwords, coprime 32)

// ---------------------------------------------------------------------------
// sorted ascending insert into u64 K[16] (lex key = (d2bits<<32)|idx)
// ---------------------------------------------------------------------------
__device__ __forceinline__ void ins16(unsigned long long* K, unsigned long long key) {
  if (key < K[15]) {
#pragma unroll
    for (int q = 15; q >= 1; --q) {
      bool ltm = key < K[q - 1];
      bool ltk = key < K[q];
      K[q] = ltm ? K[q - 1] : (ltk ? key : K[q]);
    }
    if (key < K[0]) K[0] = key;
  }
}

#define JROT(App, Aqq, Apq, Arp, Arq, V0p, V0q, V1p, V1q, V2p, V2q)            \
  do {                                                                         \
    double apq_ = Apq;                                                         \
    if (fabs(apq_) > 1e-300) {                                                 \
      double tau_ = (Aqq - App) / (2.0 * apq_);                                \
      double t_ = (tau_ >= 0.0) ? 1.0 / (tau_ + sqrt(1.0 + tau_ * tau_))       \
                                : 1.0 / (tau_ - sqrt(1.0 + tau_ * tau_));      \
      double c_ = 1.0 / sqrt(1.0 + t_ * t_);                                   \
      double s_ = t_ * c_;                                                     \
      App = App - t_ * apq_;                                                   \
      Aqq = Aqq + t_ * apq_;                                                   \
      Apq = 0.0;                                                               \
      double u_, w_;                                                           \
      u_ = Arp; w_ = Arq; Arp = c_ * u_ - s_ * w_; Arq = s_ * u_ + c_ * w_;    \
      u_ = V0p; w_ = V0q; V0p = c_ * u_ - s_ * w_; V0q = s_ * u_ + c_ * w_;    \
      u_ = V1p; w_ = V1q; V1p = c_ * u_ - s_ * w_; V1q = s_ * u_ + c_ * w_;    \
      u_ = V2p; w_ = V2q; V2p = c_ * u_ - s_ * w_; V2q = s_ * u_ + c_ * w_;    \
    }                                                                          \
  } while (0)

// ---------------------------------------------------------------------------
// Kernel T: AoS -> SoA transpose (xs, ys, zs). One-shot, ~3 µs.
// ---------------------------------------------------------------------------
__global__ __launch_bounds__(256) void soa_kernel(
    const float* __restrict__ verts,
    float* __restrict__ xs, float* __restrict__ ys, float* __restrict__ zs)
{
  const int g = blockIdx.x * 256 + (int)threadIdx.x; // 0..32767
  xs[g] = verts[3 * g + 0];
  ys[g] = verts[3 * g + 1];
  zs[g] = verts[3 * g + 2];
}

// ---------------------------------------------------------------------------
// Kernel A: 16-NN selection -> nbr_idx, + per-block radius^2 reduction.
// FINAL / MEASURED-BEST (benched 288.7/288.8/288.6 µs total, knn 222 µs):
// SoA loads + 256 per-lane byte hist rows (17-dword stride, conflict-mild)
// + 64 half-octave bins (survivor tail << CAP) + ONE atomicMax per block.
// Falsified alternatives: register-u64 hist (VGPR starvation, 2.5x worse),
// 32 octave bins (CAP-overflow fallback tail, 2.7x worse), LDS-atomic hist
// (same-address serialization, 1.1x worse), 128-thread blocks (occupancy
// pinned ~40% regardless of LDS -> barrier-phase-bound, 1.03x worse).
// ---------------------------------------------------------------------------
__global__ __launch_bounds__(256, 2) void knn_select_kernel(
    const float* __restrict__ xs,           // (8*4096) SoA
    const float* __restrict__ ys,
    const float* __restrict__ zs,
    int* __restrict__ nbr_idx,              // (8*4096,16)
    unsigned int* __restrict__ rad2_bits)   // (8), f32 d2 bits, init 0
{
  __shared__ unsigned char hist[256 * HROW];      // 17408 B, lane-private rows
  __shared__ unsigned short ptot[PPB][64];        //  2048 B
  __shared__ unsigned long long surv[PPB][CAP];   // 12288 B
  __shared__ unsigned int scnt[PPB];
  __shared__ unsigned int tbl[PPB];
  __shared__ unsigned int radsh[PPB];

  const int blk = blockIdx.x;       // 2048 blocks = 8 clouds * 256
  const int cloud = blk >> 8;
  const int pbase = (blk & 255) * PPB;
  const int cb = cloud << 12;       // cloud base into SoA arrays
  const float* __restrict__ xb = xs + cb;
  const float* __restrict__ yb = ys + cb;
  const float* __restrict__ zb = zs + cb;
  const int tid = (int)threadIdx.x;

  {
    unsigned int* h32 = (unsigned int*)hist;
#pragma unroll
    for (int k = 0; k < 17; ++k) h32[tid * 17 + k] = 0u;  // own padded row
  }
  if (tid < PPB) scnt[tid] = 0u;
  __syncthreads();

  const int p = tid >> 4;           // point-in-block
  const int c = tid & 15;           // lane-in-point
  const int i = pbase + p;
  const float xi = xb[i], yi = yb[i], zi = zb[i];

  // ---- pass 1: exact-bits histogram ----------------------------------------
#pragma unroll 4
  for (int s = 0; s < CITER; ++s) {
    const int j = (s << 4) | c;
    float dx = __fsub_rn(xb[j], xi);
    float dy = __fsub_rn(yb[j], yi);
    float dz = __fsub_rn(zb[j], zi);
    float d2 = __fadd_rn(__fadd_rn(__fmul_rn(dx, dx), __fmul_rn(dy, dy)),
                         __fmul_rn(dz, dz));
    int b = (int)(__float_as_uint(d2) >> 22) - BINOFF;
    b = min(max(b, 0), 63);
    hist[tid * HROW + b] += (unsigned char)1;
  }
  __syncthreads();

  // ---- reduce lane-private rows -> per-point totals ------------------------
#pragma unroll
  for (int bq = 0; bq < 4; ++bq) {
    int b = 4 * c + bq;
    unsigned int tot = 0;
    for (int r = 0; r < 16; ++r) tot += hist[(p * 16 + r) * HROW + b];
    ptot[p][b] = (unsigned short)tot;
  }
  __syncthreads();

  // ---- exact threshold: first bin where cumcount >= 16 ---------------------
  if (c == 0) {
    unsigned int cum = 0; int B = 63;
    for (int b = 0; b < 64; ++b) {
      cum += ptot[p][b];
      if (cum >= KNN) { B = b; break; }
    }
    // bin 63 is clamped: its edge doesn't bound contents -> accept all
    tbl[p] = (B >= 63) ? 0xFFFFFFFFu : ((unsigned int)(B + 1 + BINOFF) << 22);
  }
  __syncthreads();

  // ---- pass 2: collect survivors -------------------------------------------
  {
    const unsigned int T = tbl[p];
#pragma unroll 4
    for (int s = 0; s < CITER; ++s) {
      const int j = (s << 4) | c;
      float dx = __fsub_rn(xb[j], xi);
      float dy = __fsub_rn(yb[j], yi);
      float dz = __fsub_rn(zb[j], zi);
      float d2 = __fadd_rn(__fadd_rn(__fmul_rn(dx, dx), __fmul_rn(dy, dy)),
                           __fmul_rn(dz, dz));
      unsigned int bits = __float_as_uint(d2);
      if (bits < T) {
        unsigned int pos = atomicAdd(&scnt[p], 1u);
        if (pos < CAP) surv[p][pos] = ((unsigned long long)bits << 32) | (unsigned int)j;
      }
    }
  }
  __syncthreads();

  // ---- handler lane: exact top-16 among survivors (lex == top_k order) -----
  if (c == 0) {
    unsigned long long K[KNN];
#pragma unroll
    for (int k = 0; k < KNN; ++k) K[k] = 0xFFFFFFFFFFFFFFFFull;
    const int n = (int)scnt[p];
    if (n <= CAP) {
      for (int t = 0; t < n; ++t) ins16(K, surv[p][t]);
    } else {
      // exact fallback: serial full re-scan (never expected at 64 bins)
      for (int j = 0; j < NPTS; ++j) {
        float dx = __fsub_rn(xb[j], xi);
        float dy = __fsub_rn(yb[j], yi);
        float dz = __fsub_rn(zb[j], zi);
        float d2 = __fadd_rn(__fadd_rn(__fmul_rn(dx, dx), __fmul_rn(dy, dy)),
                             __fmul_rn(dz, dz));
        ins16(K, ((unsigned long long)__float_as_uint(d2) << 32) | (unsigned int)j);
      }
    }
    const int gp = cloud * NPTS + i;
#pragma unroll
    for (int k = 0; k < KNN; ++k) nbr_idx[gp * KNN + k] = (int)(K[k] & 0xFFFFFFFFull);
    radsh[p] = (unsigned int)(K[KNN - 1] >> 32);  // 16th-NN d2 bits
  }
  __syncthreads();

  // ---- ONE atomic per block: block max of 16 per-point d2 bits -------------
  if (tid == 0) {
    unsigned int m = radsh[0];
#pragma unroll
    for (int q = 1; q < PPB; ++q) m = max(m, radsh[q]);
    atomicMax(&rad2_bits[cloud], m);
  }
}

// ---------------------------------------------------------------------------
// Kernel B: normals, 16 LANES PER POINT (scalarized, no local arrays, no
// contended atomics).
// ---------------------------------------------------------------------------
__global__ __launch_bounds__(256, 1) void normal_kernel(
    const float* __restrict__ verts,
    const int* __restrict__ nbr_idx,
    float* __restrict__ normals)            // (8*4096,3)
{
  const int t = blockIdx.x * 256 + (int)threadIdx.x; // 0 .. 524287
  const int gp = t >> 4;            // point, 0..32767
  const int c = t & 15;             // neighbor slot
  const int cloud = gp >> 12;
  const int i = gp & (NPTS - 1);
  const float* __restrict__ vb = verts + (size_t)cloud * NPTS * 3;
  const float xi = vb[3 * i + 0], yi = vb[3 * i + 1], zi = vb[3 * i + 2];

  const int id = nbr_idx[gp * KNN + c];  // coalesced: 16 consecutive per point
  const float* vp = vb + 3 * id;
  const float dx = __fsub_rn(vp[0], xi);
  const float dy = __fsub_rn(vp[1], yi);
  const float dz = __fsub_rn(vp[2], zi);
  const float d2 = __fadd_rn(__fadd_rn(__fmul_rn(dx, dx), __fmul_rn(dy, dy)),
                             __fmul_rn(dz, dz));
  const double dist = sqrt((double)d2);
  const double radius_i = __shfl(dist, 15, 16); // lane 15 of each 16-group

  double w = radius_i - dist;
  if (w < 0.0) w = 0.0;
  const double dxd = (double)dx, dyd = (double)dy, dzd = (double)dz;
  const double wx = w * dxd, wy = w * dyd;
  double c00 = wx * dxd, c01 = wx * dyd, c02 = wx * dzd;
  double c11 = wy * dyd, c12 = wy * dzd, c22 = (w * dzd) * dzd;
  double sw = w;

  // butterfly sum within the 16-lane group (xor masks < 16 stay in-group)
#pragma unroll
  for (int m = 8; m >= 1; m >>= 1) {
    c00 += __shfl_xor(c00, m);
    c01 += __shfl_xor(c01, m);
    c02 += __shfl_xor(c02, m);
    c11 += __shfl_xor(c11, m);
    c12 += __shfl_xor(c12, m);
    c22 += __shfl_xor(c22, m);
    sw  += __shfl_xor(sw,  m);
  }

  const double inv = 1.0 / (sw + 1e-8);
  c00 *= inv; c01 *= inv; c02 *= inv; c11 *= inv; c12 *= inv; c22 *= inv;

  // all 16 lanes run the identical scalar Jacobi (uniform, no divergence)
  double A00 = c00, A01 = c01, A02 = c02, A11 = c11, A12 = c12, A22 = c22;
  double v00 = 1, v01 = 0, v02 = 0,
         v10 = 0, v11 = 1, v12 = 0,
         v20 = 0, v21 = 0, v22 = 1;
  for (int sweep = 0; sweep < 8; ++sweep) {
    JROT(A00, A11, A01, A02, A12, v00, v01, v10, v11, v20, v21);
    JROT(A00, A22, A02, A01, A12, v00, v02, v10, v12, v20, v22);
    JROT(A11, A22, A12, A01, A02, v01, v02, v11, v12, v21, v22);
  }

  double nx, ny, nz;
  if (A00 <= A11 && A00 <= A22)      { nx = v00; ny = v10; nz = v20; }
  else if (A11 <= A22)               { nx = v01; ny = v11; nz = v21; }
  else                               { nx = v02; ny = v12; nz = v22; }
  const double rn = 1.0 / sqrt(nx * nx + ny * ny + nz * nz);
  nx *= rn; ny *= rn; nz *= rn;

  // sign vote: each lane contributes its own neighbor's projection sign
  const double pr = dxd * nx + dyd * ny + dzd * nz;
  int sv = (pr > 0.0) - (pr < 0.0);
#pragma unroll
  for (int m = 8; m >= 1; m >>= 1) sv += __shfl_xor(sv, m);
  if (sv < 0) { nx = -nx; ny = -ny; nz = -nz; }

  if (c == 0) {
    normals[3 * gp + 0] = (float)nx;
    normals[3 * gp + 1] = (float)ny;
    normals[3 * gp + 2] = (float)nz;
  }
}

// ---------------------------------------------------------------------------
// Kernel B1: per point, 16 flat bins + normalization denominator.
// radius = f32(sqrt_f64(max d2)) — bit-identical to old max-of-radii.
// ---------------------------------------------------------------------------
__global__ __launch_bounds__(256) void bins_kernel(
    const float* __restrict__ verts,
    const float* __restrict__ normals,
    const int* __restrict__ nbr_idx,
    const unsigned int* __restrict__ rad2_bits,
    unsigned short* __restrict__ bins,
    float* __restrict__ denoms)
{
  const int gp = blockIdx.x * 256 + threadIdx.x;
  const int cloud = gp >> 12;
  const int i = gp & (NPTS - 1);
  const float* __restrict__ vb = verts + (size_t)cloud * NPTS * 3;
  const float xi = vb[3 * i + 0], yi = vb[3 * i + 1], zi = vb[3 * i + 2];
  const float nxi = normals[3 * gp + 0];
  const float nyi = normals[3 * gp + 1];
  const float nzi = normals[3 * gp + 2];
  const float radius = (float)sqrt((double)__uint_as_float(rad2_bits[cloud]));
  const float rpe = __fadd_rn(radius, 1e-8f);
  const float PI_F = 3.14159274101257324f;
  const float TWOPI_F = 6.28318548202514648f;

  int bl[KNN];
#pragma unroll
  for (int k = 0; k < KNN; ++k) {
    int j = nbr_idx[gp * KNN + k];
    float dx = __fsub_rn(vb[3 * j + 0], xi);
    float dy = __fsub_rn(vb[3 * j + 1], yi);
    float dz = __fsub_rn(vb[3 * j + 2], zi);
    float d2f = __fadd_rn(__fadd_rn(__fmul_rn(dx, dx), __fmul_rn(dy, dy)),
                          __fmul_rn(dz, dz));
    float r = (float)sqrt((double)d2f);

    float az = (float)atan2((double)dy, (double)dx);
    int azb = (int)__fmul_rn(__fdiv_rn(__fadd_rn(az, PI_F), TWOPI_F), 8.0f);
    azb = min(max(azb, 0), 7);

    float el = __fmul_rn(__fadd_rn(__fdiv_rn(dz, __fadd_rn(r, 1e-8f)), 1.0f), 0.5f);
    int elb = (int)__fmul_rn(el, 2.0f);
    elb = min(max(elb, 0), 1);

    int rb = (int)__fmul_rn(__fdiv_rn(r, rpe), 2.0f);
    rb = min(max(rb, 0), 1);

    int gj = cloud * NPTS + j;
    double cd = (double)nxi * (double)normals[3 * gj + 0] +
                (double)nyi * (double)normals[3 * gj + 1] +
                (double)nzi * (double)normals[3 * gj + 2];
    cd = fmin(fmax(cd, -1.0), 1.0);
    float cf = (float)cd;
    int hb = (int)__fmul_rn(__fmul_rn(__fadd_rn(cf, 1.0f), 0.5f), 11.0f);
    hb = min(max(hb, 0), 10);

    bl[k] = ((azb * 2 + elb) * 2 + rb) * 11 + hb;
  }

  int pairs = 0;
#pragma unroll
  for (int a = 0; a < KNN; ++a)
#pragma unroll
    for (int b = 0; b < KNN; ++b) pairs += (bl[a] == bl[b]) ? 1 : 0;

  denoms[gp] = __fadd_rn(sqrtf((float)pairs), 1e-8f);
  unsigned short* bp = bins + (size_t)gp * KNN;
#pragma unroll
  for (int k = 0; k < KNN; ++k) bp[k] = (unsigned short)bl[k];
}

// ---------------------------------------------------------------------------
// Kernel B2: expand to dense (8,4096,352) output.
// ---------------------------------------------------------------------------
__global__ __launch_bounds__(256) void out_kernel(
    const unsigned short* __restrict__ bins,
    const float* __restrict__ denoms,
    float* __restrict__ out)
{
  const int gid = blockIdx.x * 256 + threadIdx.x;
  const int p = gid / TBINS;
  const int b = gid - p * TBINS;
  const unsigned short* __restrict__ bp = bins + (size_t)p * KNN;
  int c = 0;
#pragma unroll
  for (int k = 0; k < KNN; ++k) c += (bp[k] == (unsigned short)b) ? 1 : 0;
  out[gid] = __fdiv_rn((float)c, denoms[p]);
}

// ---------------------------------------------------------------------------
extern "C" void kernel_launch(void* const* d_in, const int* in_sizes, int n_in,
                              void* d_out, int out_size, void* d_ws, size_t ws_size,
                              hipStream_t stream) {
  const float* verts = (const float*)d_in[0];
  float* out = (float*)d_out;

  char* ws = (char*)d_ws;
  float* normals = (float*)ws;                              // 384 KiB
  int* nidx = (int*)(ws + 393216);                          // 2 MiB
  unsigned short* bins = (unsigned short*)(ws + 2490368);   // 1 MiB
  float* denoms = (float*)(ws + 3538944);                   // 128 KiB
  unsigned int* radb = (unsigned int*)(ws + 3670016);       // 32 B
  float* xs = (float*)(ws + 3670048);                       // 128 KiB
  float* ys = (float*)(ws + 3801120);                       // 128 KiB
  float* zs = (float*)(ws + 3932192);                       // 128 KiB

  hipMemsetAsync(radb, 0, 8 * sizeof(unsigned int), stream);

  soa_kernel<<<128, 256, 0, stream>>>(verts, xs, ys, zs);
  knn_select_kernel<<<2048, 256, 0, stream>>>(xs, ys, zs, nidx, radb);
  normal_kernel<<<2048, 256, 0, stream>>>(verts, nidx, normals);
  bins_kernel<<<128, 256, 0, stream>>>(verts, normals, nidx, radb, bins, denoms);
  const int total = 8 * NPTS * TBINS;
  out_kernel<<<total / 256, 256, 0, stream>>>(bins, denoms, out);
}